// Round 1
// 1321.160 us; speedup vs baseline: 1.4348x; 1.4348x over previous
//
#include <hip/hip_runtime.h>
#include <hip/hip_bf16.h>

#define BB 8
#define HH 256
#define WW 256
#define HW 65536

typedef __attribute__((ext_vector_type(8))) short bf16x8;
typedef __attribute__((ext_vector_type(4))) float f32x4;
typedef __attribute__((ext_vector_type(8))) unsigned short u16x8;
#define MFMA16(a, b, c) __builtin_amdgcn_mfma_f32_16x16x32_bf16(a, b, c, 0, 0, 0)

__device__ __forceinline__ ushort f2bf(float f) {
  union { float f; uint32_t u; } c; c.f = f;
  uint32_t r = (c.u + 0x7fffu + ((c.u >> 16) & 1u)) >> 16;
  return (ushort)r;
}

// ---------------- workspace layout (bytes) ----------------
#define OFF_XG    0            // xg unique-maps bf16: 8*24*65536*2 = 25,165,824 (region sized 69MB)
#define OFF_XGN   69206016     // xg NHWC bf16 (72ch padded):   = 75,497,472
#define OFF_OUT1  144703488    // out1 f32: 8*65536*4           = 2,097,152
#define OFF_POOL  146800640    // pooled sums f32: 8*128*9*4    = 36,864
#define OFF_KERN  146837504    // kern f32: 8*1323*4            = 42,336 (+pad)
#define OFF_BW    146880000    // Bw bf16: [cc(2)][t9][o80][32]; alloc 138,240
#define OFF_BWZ   147018240    // BwZ bf16: 2*80*32*2           = 10,240
#define OFF_BP    147028480    // Bp bf16: 12*128*32*2          = 98,304
#define OFF_BIAS  147126784    // bias_tot f32: 80*4 (+pad)
#define OFF_TB    147127296    // TB f32: 66*9*4 (+pad)
#define OFF_T     147129856    // T f32: 66*81*4 (+pad)
#define OFF_OFFP  147151360    // offp i32: 384*4

// ---------------------------------------------------------------------------
// prepA: T, TB, Bw (gauss-chunk weights), Bp (pred1 weights), offp (im2col LUT)
// ---------------------------------------------------------------------------
__global__ __launch_bounds__(256) void k_prepA(const float* __restrict__ fuw,
                                               const float* __restrict__ trw,
                                               const float* __restrict__ trb,
                                               const float* __restrict__ p1w,
                                               float* __restrict__ T,
                                               float* __restrict__ TB,
                                               ushort* __restrict__ Bw,
                                               ushort* __restrict__ Bp,
                                               int* __restrict__ offp) {
  int i = blockIdx.x * 256 + threadIdx.x;
  if (i < 5346) {  // T
    int o = i / 81, a = (i / 9) % 9, s = i % 9;
    float acc = 0.f;
    for (int cp = 0; cp < 66; ++cp)
      acc += fuw[(o * 132 + 66 + cp) * 9 + a] *
             (trw[(cp * 3) * 9 + s] + trw[(cp * 3 + 1) * 9 + s] + trw[(cp * 3 + 2) * 9 + s]);
    T[i] = acc; return;
  }
  i -= 5346;
  if (i < 594) {  // TB
    int o = i / 9, a = i % 9;
    float acc = 0.f;
    for (int cp = 0; cp < 66; ++cp) acc += trb[cp] * fuw[(o * 132 + 66 + cp) * 9 + a];
    TB[i] = acc; return;
  }
  i -= 594;
  if (i < 2 * 9 * 80 * 32) {  // Bw
    int cc = i / 23040, t = (i / 2560) % 9, o = (i / 32) % 80, kl = i & 31;
    int c = cc * 32 + kl;
    Bw[i] = (o < 66) ? f2bf(fuw[(o * 132 + c) * 9 + t]) : 0;
    return;
  }
  i -= 2 * 9 * 80 * 32;
  if (i < 12 * 128 * 32) {  // Bp
    int kc = i / 4096, o = (i / 32) % 128, kl = i & 31;
    int k = kc * 32 + kl;
    float v = 0.f;
    if (k < 363) { int u = k / 33, r2 = k % 33, vv = r2 / 3, c = r2 % 3;
                   v = p1w[(o * 3 + c) * 121 + u * 11 + vv]; }
    Bp[i] = f2bf(v);
    return;
  }
  i -= 12 * 128 * 32;
  if (i < 384) {  // offp
    int k = i, off = -1;
    if (k < 363) { int u = k / 33, r2 = k % 33, vv = r2 / 3, c = r2 % 3; off = u * 78 + vv * 3 + c; }
    offp[i] = off;
  }
}

__device__ __forceinline__ float W5val(int o, int d, const float* T) {
  int dy = d / 5, dx = d % 5;
  float acc = 0.f;
  for (int ua = 0; ua < 3; ++ua) {
    int us = dy - ua; if (us < 0 || us > 2) continue;
    for (int va = 0; va < 3; ++va) {
      int vs = dx - va; if (vs < 0 || vs > 2) continue;
      acc += T[(o * 9 + ua * 3 + va) * 9 + us * 3 + vs];
    }
  }
  return acc;
}

// prepB: BwZ (z-chunk weights: xg ch64/65 taps + composed 5x5 W5) and bias_tot
__global__ __launch_bounds__(256) void k_prepB(const float* __restrict__ fuw,
                                               const float* __restrict__ fub,
                                               const float* __restrict__ T,
                                               const float* __restrict__ TB,
                                               ushort* __restrict__ BwZ,
                                               float* __restrict__ bias_tot) {
  int i = blockIdx.x * 256 + threadIdx.x;
  if (i < 5120) {
    int zc = i / 2560, o = (i / 32) % 80, s = i & 31;
    float v = 0.f;
    if (o < 66) {
      if (zc == 0) {
        if (s < 18) { int ch = 64 + s / 9, a = s % 9; v = fuw[(o * 132 + ch) * 9 + a]; }
        else        { v = W5val(o, s - 18, T); }
      } else {
        if (s < 11) v = W5val(o, 14 + s, T);
      }
    }
    BwZ[i] = f2bf(v); return;
  }
  i -= 5120;
  if (i < 80) {
    float v = 0.f;
    if (i < 66) { v = fub[i]; for (int a = 0; a < 9; ++a) v += TB[i * 9 + a]; }
    bias_tot[i] = v;
  }
}

__global__ void k_zero(float* p, int n) {
  int i = blockIdx.x * 256 + threadIdx.x;
  if (i < n) p[i] = 0.f;
}

// ---------------------------------------------------------------------------
// Kernel A: x_gauss — REWRITTEN.
//  * Only 24 unique (input-channel g, kernel-index j) maps exist (w_gauss is
//    np.repeat(base,3): channel o uses weight base[o/3] and input ch o/22).
//    We compute the 24 unique maps; k_tr fans them out to 66 channels.
//  * 8 outputs/thread (256-wide row tile) -> b128 LDS reads amortized 2x.
//  * LDS tile XOR-swizzled (float idx f ^= ((f>>5)&1)<<2) so the 8-float lane
//    stride gives conflict-free ds_read_b128 phases.
//  * kw-loop restricted to the ks-wide nonzero window (templated on KS so all
//    register-array indexing stays compile-time constant).
//  * weights read directly from global via wave-uniform (s_load) addresses.
// ---------------------------------------------------------------------------
template <int KS>
__device__ __forceinline__ void xg_conv(const float* __restrict__ xt,
                                        const float* __restrict__ wgp,
                                        float* a, int r, int wq) {
  constexpr int P0 = (21 - KS) / 2;
  constexpr int Q0 = P0 & ~3;
  constexpr int D0 = P0 - Q0;
  constexpr int NL = ((P0 + KS + 6) >> 2) - (P0 >> 2) + 1;
#pragma unroll 1
  for (int kh = P0; kh < P0 + KS; ++kh) {
    float rx[NL * 4];
    const int F0 = (r + kh) * 320 + 8 * wq + Q0;
#pragma unroll
    for (int i = 0; i < NL; ++i) {
      int Fi = F0 + 4 * i;
      *(float4*)(rx + 4 * i) = *(const float4*)(xt + (Fi ^ (((Fi >> 5) & 1) << 2)));
    }
    const float* wr = wgp + kh * 21 + P0;  // wave-uniform -> scalar loads
#pragma unroll
    for (int t = 0; t < KS; ++t) {
      float wv = wr[t];
#pragma unroll
      for (int u = 0; u < 8; ++u) a[u] += wv * rx[D0 + t + u];
    }
  }
}

__global__ __launch_bounds__(256, 4) void k_xgauss(const float* __restrict__ x,
                                                   const float* __restrict__ wg,
                                                   __hip_bfloat16* __restrict__ xg) {
  const int bu = blockIdx.z;
  const int b = bu / 24, u = bu % 24;
  const int g = u >> 3;              // input channel
  const int j = (u & 7) + 7 * g;     // kernel index (o/3)
  const int h0 = blockIdx.y * 8;
  __shared__ __align__(16) float xt[28 * 320];
  const float* xp = x + (b * 3 + g) * HW;
  for (int e = threadIdx.x; e < 28 * 320; e += 256) {
    int row = e / 320, col = e % 320;
    int gy = h0 + row - 10, gx = col - 10;
    float v = (gy >= 0 && gy < HH && gx >= 0 && gx < WW) ? xp[gy * WW + gx] : 0.f;
    xt[e ^ (((e >> 5) & 1) << 2)] = v;
  }
  __syncthreads();
  int i_ = j - 1;
  int im = (i_ - 1 > 0) ? (i_ - 1) : 0;
  const int ks = (j == 0) ? 1 : 3 + 2 * (im >> 1);
  const int wq = threadIdx.x & 31, r = threadIdx.x >> 5;
  const float* wgp = wg + (3 * j) * 441;
  float a[8] = {0.f, 0.f, 0.f, 0.f, 0.f, 0.f, 0.f, 0.f};
  switch (ks) {
    case 1:  xg_conv<1>(xt, wgp, a, r, wq); break;
    case 3:  xg_conv<3>(xt, wgp, a, r, wq); break;
    case 5:  xg_conv<5>(xt, wgp, a, r, wq); break;
    case 7:  xg_conv<7>(xt, wgp, a, r, wq); break;
    case 9:  xg_conv<9>(xt, wgp, a, r, wq); break;
    case 11: xg_conv<11>(xt, wgp, a, r, wq); break;
    case 13: xg_conv<13>(xt, wgp, a, r, wq); break;
    case 15: xg_conv<15>(xt, wgp, a, r, wq); break;
    case 17: xg_conv<17>(xt, wgp, a, r, wq); break;
    case 19: xg_conv<19>(xt, wgp, a, r, wq); break;
    default: xg_conv<21>(xt, wgp, a, r, wq); break;
  }
  u16x8 ov;
#pragma unroll
  for (int k = 0; k < 8; ++k) ov[k] = f2bf(a[k]);
  int oidx = (bu * HW) + (h0 + r) * WW + 8 * wq;
  *(u16x8*)((ushort*)xg + oidx) = ov;
}

// ---------------------------------------------------------------------------
// Transpose xg unique-maps -> NHWC (72-ch padded), fanning 24 maps out to 66
// channels: channel c reads unique map uid = c/3 + c/22.
// ---------------------------------------------------------------------------
__global__ __launch_bounds__(256) void k_tr(const ushort* __restrict__ xg,
                                            ushort* __restrict__ xgn) {
  __shared__ ushort ls[64 * 72];
  int p0 = blockIdx.x * 64;
  int b = p0 >> 16, sp = p0 & 65535;
  for (int e = threadIdx.x; e < 72 * 64; e += 256) {
    int c = e >> 6, i = e & 63;
    int uc = c / 3 + c / 22;
    ls[i * 72 + c] = (c < 66) ? xg[(size_t)(b * 24 + uc) * HW + sp + i] : (ushort)0;
  }
  __syncthreads();
  for (int e = threadIdx.x; e < 576; e += 256) {
    *(float4*)(xgn + (size_t)p0 * 72 + e * 8) = *(const float4*)(ls + e * 8);
  }
}

// ---------------------------------------------------------------------------
// Predictor stage 1 as MFMA implicit GEMM (unchanged)
// ---------------------------------------------------------------------------
__global__ __launch_bounds__(256, 2) void k_pmm(const float* __restrict__ x,
                                                const ushort* __restrict__ Bp,
                                                const int* __restrict__ offp,
                                                const float* __restrict__ p1b,
                                                float* __restrict__ pooled) {
  __shared__ float xt[26 * 26 * 3];
  __shared__ ushort az[256 * 32];
  __shared__ float ps[1152];
  const int b = blockIdx.z, h0 = blockIdx.y * 16, w0 = blockIdx.x * 16;
  const int tid = threadIdx.x, wave = tid >> 6, lane = tid & 63;
  const int m = lane & 15, q = lane >> 4;
  for (int e = tid; e < 1152; e += 256) ps[e] = 0.f;
  for (int e = tid; e < 676; e += 256) {
    int py = e / 26, pxc = e % 26, gy = h0 - 2 + py, gx = w0 - 2 + pxc;
    bool in = (gy >= 0 && gy < HH && gx >= 0 && gx < WW);
#pragma unroll
    for (int c = 0; c < 3; ++c)
      xt[e * 3 + c] = in ? x[(b * 3 + c) * HW + gy * WW + gx] : 0.f;
  }
  f32x4 acc[4][8];
#pragma unroll
  for (int a = 0; a < 4; ++a)
#pragma unroll
    for (int n = 0; n < 8; ++n) acc[a][n] = (f32x4){0.f, 0.f, 0.f, 0.f};
  const int py = tid >> 4, pxc = tid & 15;
  const int pbase = (py * 26 + pxc) * 3;
  __syncthreads();
  for (int kc = 0; kc < 12; ++kc) {
    union { ushort us[32]; float4 f4[4]; } vals;
#pragma unroll
    for (int kl = 0; kl < 32; ++kl) {
      int off = offp[kc * 32 + kl];  // wave-uniform -> s_load
      vals.us[kl] = f2bf((off >= 0) ? xt[pbase + off] : 0.f);
    }
    if (kc) __syncthreads();
#pragma unroll
    for (int u = 0; u < 4; ++u)
      *(float4*)(az + tid * 32 + ((u ^ (tid & 3)) << 3)) = vals.f4[u];
    __syncthreads();
    bf16x8 bf[8];
#pragma unroll
    for (int nt = 0; nt < 8; ++nt)
      bf[nt] = *(const bf16x8*)(Bp + ((kc * 128 + nt * 16 + m) * 32 + q * 8));
#pragma unroll
    for (int mt = 0; mt < 4; ++mt) {
      int px = (((wave << 2) + mt) << 4) + m;
      bf16x8 af = *(const bf16x8*)(az + px * 32 + ((q ^ (px & 3)) << 3));
#pragma unroll
      for (int nt = 0; nt < 8; ++nt)
        acc[mt][nt] = MFMA16(af, bf[nt], acc[mt][nt]);
    }
  }
  float bv[8];
#pragma unroll
  for (int nt = 0; nt < 8; ++nt) bv[nt] = p1b[nt * 16 + m];
#pragma unroll
  for (int mt = 0; mt < 4; ++mt) {
    int h = h0 + (wave << 2) + mt;
    if (h >= 250) continue;
    bool h0m = h < 84, h1m = (h >= 83 && h < 167), h2m = h >= 166;
#pragma unroll
    for (int r = 0; r < 4; ++r) {
      int w = w0 + (q << 2) + r;
      if (w >= 250) continue;
      bool w0m = w < 84, w1m = (w >= 83 && w < 167), w2m = w >= 166;
#pragma unroll
      for (int nt = 0; nt < 8; ++nt) {
        int o = (nt << 4) + m;
        float vz = acc[mt][nt][r] + bv[nt];
        vz = vz >= 0.f ? vz : 0.2f * vz;
        if (h0m) { if (w0m) atomicAdd(&ps[o], vz);        if (w1m) atomicAdd(&ps[128 + o], vz);
                   if (w2m) atomicAdd(&ps[256 + o], vz); }
        if (h1m) { if (w0m) atomicAdd(&ps[384 + o], vz);  if (w1m) atomicAdd(&ps[512 + o], vz);
                   if (w2m) atomicAdd(&ps[640 + o], vz); }
        if (h2m) { if (w0m) atomicAdd(&ps[768 + o], vz);  if (w1m) atomicAdd(&ps[896 + o], vz);
                   if (w2m) atomicAdd(&ps[1024 + o], vz); }
      }
    }
  }
  __syncthreads();
  for (int e = tid; e < 1152; e += 256)
    atomicAdd(&pooled[b * 1152 + e], ps[(e % 9) * 128 + (e / 9)]);
}

// ---------------------------------------------------------------------------
// Predictor tail (unchanged)
// ---------------------------------------------------------------------------
__global__ __launch_bounds__(256) void k_pred2(const float* __restrict__ pooled,
                                               const float* __restrict__ p2w,
                                               const float* __restrict__ p3w,
                                               float* __restrict__ kernw) {
  const int b = blockIdx.x;
  const int tid = threadIdx.x;
  __shared__ float hin[1152];
  __shared__ float h2p[1323];
  __shared__ float h3l[1323];
  __shared__ float mx[3], sm[3];
  for (int e = tid; e < 1152; e += 256) hin[e] = pooled[b * 1152 + e] * (1.f / 7056.f);
  __syncthreads();
  for (int c = tid; c < 441; c += 256) {
    float z[9] = {0.f,0.f,0.f,0.f,0.f,0.f,0.f,0.f,0.f};
    const float* wr = p2w + c * 128;
    for (int k = 0; k < 128; k++) {
      float wv = wr[k];
      const float* hp = &hin[k * 9];
#pragma unroll
      for (int p = 0; p < 9; p++) z[p] += wv * hp[p];
    }
#pragma unroll
    for (int i = 0; i < 3; i++) {
      float s = 0.f;
#pragma unroll
      for (int jj = 0; jj < 3; jj++) {
        float zz = z[i * 3 + jj];
        s += (zz >= 0.f) ? zz : 0.2f * zz;
      }
      h2p[c * 3 + i] = s * (1.f / 3.f);
    }
  }
  __syncthreads();
  for (int c = tid; c < 441; c += 256) {
    float a0 = 0.f, a1 = 0.f, a2 = 0.f;
    const float* wr = p3w + c * 441;
    for (int k = 0; k < 441; k++) {
      float wv = wr[k];
      a0 += wv * h2p[k * 3];
      a1 += wv * h2p[k * 3 + 1];
      a2 += wv * h2p[k * 3 + 2];
    }
    h3l[c * 3] = a0; h3l[c * 3 + 1] = a1; h3l[c * 3 + 2] = a2;
  }
  __syncthreads();
  if (tid < 3) {
    float mxv = -1e30f;
    for (int c = 0; c < 441; c++) mxv = fmaxf(mxv, h3l[c * 3 + tid]);
    float s = 0.f;
    for (int c = 0; c < 441; c++) s += expf(h3l[c * 3 + tid] - mxv);
    mx[tid] = mxv; sm[tid] = 1.f / s;
  }
  __syncthreads();
  for (int f = tid; f < 1323; f += 256) {
    int i = f % 3;
    kernw[b * 1323 + f] = expf(h3l[f] - mx[i]) * sm[i];
  }
}

// ---------------------------------------------------------------------------
// Kernel D: per-sample dynamic conv (unchanged)
// ---------------------------------------------------------------------------
__global__ __launch_bounds__(256) void k_dyn(const float* __restrict__ x,
                                             const float* __restrict__ kernw,
                                             float* __restrict__ out1) {
  const int b = blockIdx.z;
  const int h0 = blockIdx.y * 16, w0 = blockIdx.x * 64;
  __shared__ float kl[1323];
  __shared__ float xt[3 * 36 * 84];
  for (int e = threadIdx.x; e < 1323; e += 256) kl[e] = kernw[b * 1323 + e];
  for (int e = threadIdx.x; e < 3 * 36 * 84; e += 256) {
    int ci = e / 3024, rem = e % 3024;
    int ty = rem / 84, tx = rem % 84;
    int gy = h0 + ty - 10, gx = w0 + tx - 10;
    xt[e] = (gy >= 0 && gy < HH && gx >= 0 && gx < WW)
                ? x[(b * 3 + ci) * HW + gy * WW + gx] : 0.f;
  }
  __syncthreads();
  const int wq = threadIdx.x & 15, r = threadIdx.x >> 4;
  float a0 = 0.f, a1 = 0.f, a2 = 0.f, a3 = 0.f;
  for (int ci = 0; ci < 3; ci++) {
    for (int kh = 0; kh < 21; kh++) {
      float rx[24];
      const float4* rp = (const float4*)&xt[ci * 3024 + (r + kh) * 84 + 4 * wq];
      float4* rv = (float4*)rx;
#pragma unroll
      for (int i = 0; i < 6; i++) rv[i] = rp[i];
      const float* wr = &kl[ci * 441 + kh * 21];
#pragma unroll
      for (int kw = 0; kw < 21; kw++) {
        float wv = wr[kw];
        a0 += wv * rx[kw];     a1 += wv * rx[kw + 1];
        a2 += wv * rx[kw + 2]; a3 += wv * rx[kw + 3];
      }
    }
  }
  int idx = b * HW + (h0 + r) * WW + w0 + 4 * wq;
  *(float4*)&out1[idx] = make_float4(a0, a1, a2, a3);
}

// ---------------------------------------------------------------------------
// Kernel E: ax_out (unchanged)
// ---------------------------------------------------------------------------
__global__ __launch_bounds__(256) void k_ax(const float* __restrict__ x,
                                            const float* __restrict__ csw,
                                            const float* __restrict__ csb,
                                            float* __restrict__ out2) {
  int idx = blockIdx.x * 256 + threadIdx.x;
  if (idx >= BB * 3 * HW) return;
  int w = idx & 255, h = (idx >> 8) & 255;
  int oc = (idx >> 16) % 3, b = idx / (3 * HW);
  float acc = csb[oc];
  for (int ic = 0; ic < 3; ic++) {
    const float* xc = x + (b * 3 + ic) * HW;
    const float* wp = csw + (oc * 3 + ic) * 9;
#pragma unroll
    for (int u = 0; u < 3; u++) {
      int iy = h + u - 1;
      if (iy < 0 || iy >= HH) continue;
#pragma unroll
      for (int v = 0; v < 3; v++) {
        int ix = w + v - 1;
        if (ix >= 0 && ix < WW) acc += xc[iy * WW + ix] * wp[u * 3 + v];
      }
    }
  }
  out2[idx] = acc;
}

// ---------------------------------------------------------------------------
// Fused conv as MFMA implicit GEMM (unchanged)
// ---------------------------------------------------------------------------
__global__ __launch_bounds__(256, 3) void k_fmma(const ushort* __restrict__ xgn,
                                                 const float* __restrict__ out1,
                                                 const ushort* __restrict__ Bw,
                                                 const ushort* __restrict__ BwZ,
                                                 const float* __restrict__ bias_tot,
                                                 float* __restrict__ outf) {
  __shared__ __align__(16) char smem[40080];
  ushort* xs  = (ushort*)smem;               // 18*18*32 bf16 = 20736
  float*  o1s = (float*)(smem + 20736);      // 20*20 f32     = 1600
  ushort* xs2 = (ushort*)(smem + 22336);     // 18*18*2 bf16  = 1296
  ushort* az  = (ushort*)(smem + 23632);     // 256*32 bf16   = 16384
  float*  st  = (float*)(smem + 23632);      // 16*257 f32    = 16448 (aliases az)
  const int b = blockIdx.z, h0 = blockIdx.y * 16, w0 = blockIdx.x * 16;
  const int tid = threadIdx.x, wave = tid >> 6, lane = tid & 63;
  const int m = lane & 15, q = lane >> 4;
  f32x4 acc[4][5];
#pragma unroll
  for (int a = 0; a < 4; ++a)
#pragma unroll
    for (int n = 0; n < 5; ++n) acc[a][n] = (f32x4){0.f, 0.f, 0.f, 0.f};

  for (int cc = 0; cc < 2; ++cc) {
    __syncthreads();
    for (int e = tid; e < 1296; e += 256) {
      int u = e & 3, p = e >> 2, py = p / 18, px = p % 18;
      int gy = h0 - 1 + py, gx = w0 - 1 + px;
      float4 v = make_float4(0.f, 0.f, 0.f, 0.f);
      if (gy >= 0 && gy < HH && gx >= 0 && gx < WW)
        v = *(const float4*)(xgn + (size_t)(b * HW + gy * WW + gx) * 72 + cc * 32 + u * 8);
      *(float4*)(xs + p * 32 + u * 8) = v;
    }
    __syncthreads();
#pragma unroll
    for (int t = 0; t < 9; ++t) {
      const int u = t / 3, v = t % 3;
      bf16x8 bf[5];
#pragma unroll
      for (int nt = 0; nt < 5; ++nt)
        bf[nt] = *(const bf16x8*)(Bw + (((cc * 9 + t) * 80 + nt * 16 + m) * 32 + q * 8));
#pragma unroll
      for (int mt = 0; mt < 4; ++mt) {
        int row = (wave << 2) + mt;
        bf16x8 af = *(const bf16x8*)(xs + ((row + u) * 18 + m + v) * 32 + q * 8);
#pragma unroll
        for (int nt = 0; nt < 5; ++nt)
          acc[mt][nt] = MFMA16(af, bf[nt], acc[mt][nt]);
      }
    }
  }
  __syncthreads();
  for (int e = tid; e < 324; e += 256) {
    int py = e / 18, px = e % 18, gy = h0 - 1 + py, gx = w0 - 1 + px;
    uint32_t v = 0;
    if (gy >= 0 && gy < HH && gx >= 0 && gx < WW)
      v = *(const uint32_t*)(xgn + (size_t)(b * HW + gy * WW + gx) * 72 + 64);
    *(uint32_t*)(xs2 + e * 2) = v;
  }
  for (int e = tid; e < 400; e += 256) {
    int py = e / 20, px = e % 20, gy = h0 - 2 + py, gx = w0 - 2 + px;
    o1s[e] = (gy >= 0 && gy < HH && gx >= 0 && gx < WW) ? out1[b * HW + gy * WW + gx] : 0.f;
  }
  __syncthreads();
  const int bpy = tid >> 4, bpx = tid & 15;
#pragma unroll
  for (int zc = 0; zc < 2; ++zc) {
    union { ushort us[32]; float4 f4[4]; } vals;
    if (zc == 0) {
#pragma unroll
      for (int s = 0; s < 18; ++s) {
        int ch = s / 9, a = s % 9, u = a / 3, v = a % 3;
        vals.us[s] = xs2[((bpy + u) * 18 + bpx + v) * 2 + ch];
      }
#pragma unroll
      for (int d = 0; d < 14; ++d)
        vals.us[18 + d] = f2bf(o1s[(bpy + d / 5) * 20 + bpx + d % 5]);
    } else {
#pragma unroll
      for (int s = 0; s < 11; ++s) {
        int d = 14 + s;
        vals.us[s] = f2bf(o1s[(bpy + d / 5) * 20 + bpx + d % 5]);
      }
#pragma unroll
      for (int s = 11; s < 32; ++s) vals.us[s] = 0;
    }
    __syncthreads();
#pragma unroll
    for (int u = 0; u < 4; ++u)
      *(float4*)(az + tid * 32 + ((u ^ (tid & 3)) << 3)) = vals.f4[u];
    __syncthreads();
    bf16x8 bf[5];
#pragma unroll
    for (int nt = 0; nt < 5; ++nt)
      bf[nt] = *(const bf16x8*)(BwZ + ((zc * 80 + nt * 16 + m) * 32 + q * 8));
#pragma unroll
    for (int mt = 0; mt < 4; ++mt) {
      int px = (((wave << 2) + mt) << 4) + m;
      bf16x8 af = *(const bf16x8*)(az + px * 32 + ((q ^ (px & 3)) << 3));
#pragma unroll
      for (int nt = 0; nt < 5; ++nt)
        acc[mt][nt] = MFMA16(af, bf[nt], acc[mt][nt]);
    }
  }
#pragma unroll 1
  for (int nt = 0; nt < 5; ++nt) {
    __syncthreads();
#pragma unroll
    for (int mt = 0; mt < 4; ++mt) {
      int pxb = (((wave << 2) + mt) << 4);
#pragma unroll
      for (int r = 0; r < 4; ++r)
        st[m * 257 + pxb + q * 4 + r] = acc[mt][nt][r];
    }
    __syncthreads();
#pragma unroll
    for (int kk = 0; kk < 16; ++kk) {
      int o = nt * 16 + kk;
      if (o < 66) {
        float bvv = bias_tot[o];
        outf[((b * 66 + o) * HH + h0 + (tid >> 4)) * WW + w0 + (tid & 15)] =
            st[kk * 257 + tid] + bvv;
      }
    }
  }
}

// ---------------------------------------------------------------------------
// Border fixup (unchanged)
// ---------------------------------------------------------------------------
__global__ __launch_bounds__(256) void k_fix(const float* __restrict__ out1,
                                             const float* __restrict__ T,
                                             const float* __restrict__ TB,
                                             float* __restrict__ outf) {
  int idx = blockIdx.x * 256 + threadIdx.x;
  if (idx >= 8 * 1020 * 66) return;
  int b = idx / (1020 * 66);
  int rem = idx % (1020 * 66);
  int pi = rem / 66, o = rem % 66;
  int ph, pw;
  if (pi < 256)      { ph = 0;        pw = pi; }
  else if (pi < 512) { ph = 255;      pw = pi - 256; }
  else if (pi < 766) { ph = pi - 511; pw = 0; }
  else               { ph = pi - 765; pw = 255; }
  float corr = 0.f;
#pragma unroll
  for (int a = 0; a < 9; ++a) {
    int ua = a / 3, va = a % 3;
    int qh = ph + ua - 1, qw = pw + va - 1;
    if (qh >= 0 && qh < HH && qw >= 0 && qw < WW) continue;
    float s = TB[o * 9 + a];
#pragma unroll
    for (int t2 = 0; t2 < 9; ++t2) {
      int rh = qh + t2 / 3 - 1, rw = qw + t2 % 3 - 1;
      if (rh >= 0 && rh < HH && rw >= 0 && rw < WW)
        s += out1[b * HW + rh * WW + rw] * T[(o * 9 + a) * 9 + t2];
    }
    corr += s;
  }
  outf[((b * 66 + o) * HH + ph) * WW + pw] -= corr;
}

// ---------------------------------------------------------------------------
extern "C" void kernel_launch(void* const* d_in, const int* in_sizes, int n_in,
                              void* d_out, int out_size, void* d_ws, size_t ws_size,
                              hipStream_t stream) {
  const float* x   = (const float*)d_in[0];
  const float* wg  = (const float*)d_in[1];
  const float* p1w = (const float*)d_in[2];
  const float* p1b = (const float*)d_in[3];
  const float* p2w = (const float*)d_in[4];
  const float* p3w = (const float*)d_in[5];
  const float* csw = (const float*)d_in[6];
  const float* csb = (const float*)d_in[7];
  const float* trw = (const float*)d_in[8];
  const float* trb = (const float*)d_in[9];
  const float* fuw = (const float*)d_in[10];
  const float* fub = (const float*)d_in[11];
  float* outf = (float*)d_out;                 // fused: 8*66*256*256
  float* out2 = outf + 34603008;               // ax_out: 8*3*256*256
  char* ws = (char*)d_ws;
  __hip_bfloat16* xg = (__hip_bfloat16*)(ws + OFF_XG);
  ushort* xgn    = (ushort*)(ws + OFF_XGN);
  float* out1    = (float*)(ws + OFF_OUT1);
  float* pooled  = (float*)(ws + OFF_POOL);
  float* kernw   = (float*)(ws + OFF_KERN);
  ushort* Bw     = (ushort*)(ws + OFF_BW);
  ushort* BwZ    = (ushort*)(ws + OFF_BWZ);
  ushort* Bp     = (ushort*)(ws + OFF_BP);
  float* biasT   = (float*)(ws + OFF_BIAS);
  float* TBp     = (float*)(ws + OFF_TB);
  float* Tp      = (float*)(ws + OFF_T);
  int*   offp    = (int*)(ws + OFF_OFFP);

  hipLaunchKernelGGL(k_prepA, dim3(397), dim3(256), 0, stream,
                     fuw, trw, trb, p1w, Tp, TBp, Bw, Bp, offp);
  hipLaunchKernelGGL(k_prepB, dim3(21), dim3(256), 0, stream,
                     fuw, fub, Tp, TBp, BwZ, biasT);
  hipLaunchKernelGGL(k_zero, dim3(36), dim3(256), 0, stream, pooled, 9216);
  hipLaunchKernelGGL(k_xgauss, dim3(1, 32, 8 * 24), dim3(256), 0, stream, x, wg, xg);
  hipLaunchKernelGGL(k_tr, dim3(8192), dim3(256), 0, stream, (const ushort*)xg, xgn);
  hipLaunchKernelGGL(k_pmm, dim3(16, 16, 8), dim3(256), 0, stream, x, Bp, offp, p1b, pooled);
  hipLaunchKernelGGL(k_pred2, dim3(8), dim3(256), 0, stream, pooled, p2w, p3w, kernw);
  hipLaunchKernelGGL(k_dyn, dim3(4, 16, 8), dim3(256), 0, stream, x, kernw, out1);
  hipLaunchKernelGGL(k_fmma, dim3(16, 16, 8), dim3(256), 0, stream,
                     xgn, out1, Bw, BwZ, biasT, outf);
  hipLaunchKernelGGL(k_fix, dim3(2104), dim3(256), 0, stream, out1, Tp, TBp, outf);
  hipLaunchKernelGGL(k_ax, dim3(6144), dim3(256), 0, stream, x, csw, csb, out2);
}